// Round 7
// baseline (467.714 us; speedup 1.0000x reference)
//
#include <hip/hip_runtime.h>
#include <math.h>

typedef unsigned short u16;
typedef unsigned char u8;
typedef __attribute__((ext_vector_type(8))) short bf16x8;
typedef __attribute__((ext_vector_type(4))) float f32x4;
typedef __attribute__((ext_vector_type(2))) long long ll2;

#define S_N 16384
#define Q_N 4096
#define D_N 1024
#define C_N 256
#define NS 16
#define BQ 128
#define BS 128
#define BK 64
#define SRANGE (S_N / NS)     // 1024
#define NTILES (SRANGE / BS)  // 8
#define NKC (D_N / BK)        // 16
#define NTHR 512

// ---- workspace layout (bytes) ----
#define WS_MASSP   0u                                    // Q*C*4 = 4 MB
#define WS_MU      4194304u                              // D*4 raw sums (atomic)
#define WS_COUNTS  (WS_MU + 4096u)                       // C*4
#define WS_NORMS   (WS_COUNTS + 1024u)                   // S*4
#define WS_SUPPB   (WS_NORMS + 65536u)                   // S*D = 16 MB (fp8, k-interleaved)
#define WS_QB      (WS_SUPPB + 16777216u)                // Q*D = 4 MB

#define GLOAD16(g, l)                                                        \
    __builtin_amdgcn_global_load_lds(                                        \
        (const __attribute__((address_space(1))) void*)(g),                  \
        (__attribute__((address_space(3))) void*)(l), 16, 0, 0)

// 4 floats -> 4 packed fp8 e4m3 (OCP), RNE hardware cvt
__device__ __forceinline__ unsigned f2fp8x4(float a, float b, float c, float d) {
    unsigned v = __builtin_amdgcn_cvt_pk_fp8_f32(a, b, 0, false);
    v = __builtin_amdgcn_cvt_pk_fp8_f32(c, d, v, true);
    return v;
}

__device__ __forceinline__ u16 f2bf(float f) {
    unsigned x = __float_as_uint(f);
    return (u16)((x + 0x7fffu + ((x >> 16) & 1u)) >> 16);
}

// k-interleaved u32 store index within a row: chunk c of 64B K-group holds
// granules (c, c+4) -> one ds_read_b128 yields both k2 slices of a fragment
__device__ __forceinline__ int kperm(int t) {
    return (t >> 4) * 16 + ((t >> 1) & 3) * 4 + ((t >> 3) & 1) * 2 + (t & 1);
}

__device__ __forceinline__ float blkSum(float v, float* sh) {
#pragma unroll
    for (int o = 32; o; o >>= 1) v += __shfl_down(v, o);
    if ((threadIdx.x & 63) == 0) sh[threadIdx.x >> 6] = v;
    __syncthreads();
    float r = sh[0] + sh[1] + sh[2] + sh[3];
    __syncthreads();
    return r;
}

__device__ __forceinline__ float blkMax(float v, float* sh) {
#pragma unroll
    for (int o = 32; o; o >>= 1) v = fmaxf(v, __shfl_down(v, o));
    if ((threadIdx.x & 63) == 0) sh[threadIdx.x >> 6] = v;
    __syncthreads();
    float r = fmaxf(fmaxf(sh[0], sh[1]), fmaxf(sh[2], sh[3]));
    __syncthreads();
    return r;
}

// ---- fused: row norms + column sums of normalized rows (atomic mu) + counts ----
// 1024 blocks x 256 thr; block = 16 rows; wave = 4 rows
__global__ void k_prep(const float* __restrict__ sup, const int* __restrict__ lab,
                       float* __restrict__ mu_raw, float* __restrict__ norms,
                       int* __restrict__ counts) {
    __shared__ float4 shc[4][256];   // 16 KB: per-wave column partials
    int t = threadIdx.x, w = t >> 6, lane = t & 63;
    int r0 = blockIdx.x * 16;
    float4 a[4];
#pragma unroll
    for (int i = 0; i < 4; i++) a[i] = make_float4(0.f, 0.f, 0.f, 0.f);
    for (int rr = 0; rr < 4; ++rr) {
        int r = r0 + w * 4 + rr;
        const float4* rp = (const float4*)(sup + (size_t)r * D_N);
        float4 v[4];
        float ss = 0.f;
#pragma unroll
        for (int i = 0; i < 4; i++) {
            v[i] = rp[lane + 64 * i];
            ss += v[i].x * v[i].x + v[i].y * v[i].y + v[i].z * v[i].z + v[i].w * v[i].w;
        }
#pragma unroll
        for (int o = 32; o; o >>= 1) ss += __shfl_xor(ss, o);
        float n = sqrtf(ss);
        if (lane == 0) norms[r] = n;
        float inv = 1.f / fmaxf(n, 1e-8f);
#pragma unroll
        for (int i = 0; i < 4; i++) {
            a[i].x += v[i].x * inv; a[i].y += v[i].y * inv;
            a[i].z += v[i].z * inv; a[i].w += v[i].w * inv;
        }
    }
#pragma unroll
    for (int i = 0; i < 4; i++) shc[w][lane + 64 * i] = a[i];
    __syncthreads();
    {   // thread t owns float4 column-slot t
        float4 s0 = shc[0][t], s1 = shc[1][t], s2 = shc[2][t], s3 = shc[3][t];
        float sx = s0.x + s1.x + s2.x + s3.x;
        float sy = s0.y + s1.y + s2.y + s3.y;
        float sz = s0.z + s1.z + s2.z + s3.z;
        float sw = s0.w + s1.w + s2.w + s3.w;
        unsafeAtomicAdd(&mu_raw[t * 4 + 0], sx);
        unsafeAtomicAdd(&mu_raw[t * 4 + 1], sy);
        unsafeAtomicAdd(&mu_raw[t * 4 + 2], sz);
        unsafeAtomicAdd(&mu_raw[t * 4 + 3], sw);
    }
    if (t < 16) atomicAdd(&counts[lab[r0 + t]], 1);
}

// ---- merged transform: normalize, center, renormalize -> fp8 x16, k-interleaved ----
// grid S_N + Q_N blocks
__global__ void k_trans(const float* __restrict__ sup, const float* __restrict__ qry,
                        const float* __restrict__ norms, const float* __restrict__ mu_raw,
                        u8* __restrict__ suppb, u8* __restrict__ qb) {
    __shared__ float sh[4];
    int b = blockIdx.x, t = threadIdx.x;
    bool isq = b >= S_N;
    int r = isq ? (b - S_N) : b;
    const float* src = isq ? qry : sup;
    float4 x = ((const float4*)(src + (size_t)r * D_N))[t];
    float inv1;
    if (isq) {
        float ss1 = x.x * x.x + x.y * x.y + x.z * x.z + x.w * x.w;
        float tot1 = blkSum(ss1, sh);
        inv1 = 1.f / fmaxf(sqrtf(tot1), 1e-8f);
    } else {
        inv1 = 1.f / fmaxf(norms[r], 1e-8f);
    }
    float4 mr = ((const float4*)mu_raw)[t];
    const float ms = 1.f / (float)S_N;
    float4 y;
    y.x = x.x * inv1 - mr.x * ms; y.y = x.y * inv1 - mr.y * ms;
    y.z = x.z * inv1 - mr.z * ms; y.w = x.w * inv1 - mr.w * ms;
    float ss2 = y.x * y.x + y.y * y.y + y.z * y.z + y.w * y.w;
    float tot2 = blkSum(ss2, sh);
    float s16 = 16.f / fmaxf(sqrtf(tot2), 1e-8f);   // x16 centers fp8 range
    u8* outp = isq ? qb : suppb;
    ((unsigned*)(outp + (size_t)r * D_N))[kperm(t)] =
        f2fp8x4(y.x * s16, y.y * s16, y.z * s16, y.w * s16);
}

// ---- main: fp8 pipelined sims-GEMM (b128 frags) + exp(bf16 sP) + mass-GEMM ----
__launch_bounds__(NTHR, 2)
__global__ void k_mass(const u8* __restrict__ Qb, const u8* __restrict__ Sb,
                       const int* __restrict__ lab, const float* __restrict__ scale_p,
                       float* __restrict__ massp) {
    __shared__ u8 sQ[2][BQ * BK];     // 2x8 KB, linear-written, chunk-swizzled content
    __shared__ u8 sS[2][BS * BK];     // 2x8 KB
    __shared__ u16 sP[BQ * BS];       // 32 KB, exp(P) bf16, swizzled
    __shared__ int slabAll[SRANGE];   // 4 KB

    const int t = threadIdx.x;
    const int lane = t & 63, w = t >> 6;
    const int wrow = w >> 1, wcol = w & 1;      // sims wave grid 4x2 (32q x 64s / wave)
    const int l15 = lane & 15, l4 = lane >> 4;
    const int sblk = blockIdx.x >> 5;           // R4/R6 mapping (measured-best locality)
    const int qblk = blockIdx.x & 31;
    const int qbase = qblk * BQ;
    const int s0 = sblk * SRANGE;

    const float scale = fminf(fmaxf(*scale_p, 1.f), 20.f);
    const float sl2 = scale * 1.44269504f * (1.f / 256.f);  // /256 undoes x16*x16

    // staging: thread t stages LDS bytes [t*16, t*16+16) (linear);
    // row = t>>2, source 16B chunk pre-swizzled: c ^= (row>>1)&3  (rule 21)
    const int srow = t >> 2;
    const int sck = (t & 3) ^ ((srow >> 1) & 3);
    const int lofs = w * 1024;

    // fragment reads: ONE b128 per frag pair (k-interleaved rows), chunk-XOR swizzle
    int aoff[2], boff[4];
#pragma unroll
    for (int m = 0; m < 2; m++) {
        int r = wrow * 32 + m * 16 + l15;
        aoff[m] = r * 64 + ((l4 ^ ((r >> 1) & 3)) << 4);
    }
#pragma unroll
    for (int n = 0; n < 4; n++) {
        int r = wcol * 64 + n * 16 + l15;
        boff[n] = r * 64 + ((l4 ^ ((r >> 1) & 3)) << 4);
    }

    auto stage = [&](int sbase, int kc, int buf) {
        const u8* gq = Qb + (size_t)(qbase + srow) * D_N + kc * BK + sck * 16;
        const u8* gs = Sb + (size_t)(sbase + srow) * D_N + kc * BK + sck * 16;
        GLOAD16(gq, (char*)sQ[buf] + lofs);
        GLOAD16(gs, (char*)sS[buf] + lofs);
    };

    for (int i = t; i < SRANGE; i += NTHR) slabAll[i] = lab[s0 + i];
    asm volatile("s_waitcnt vmcnt(0) lgkmcnt(0)" ::: "memory");
    __builtin_amdgcn_s_barrier();

    // mass accumulator: wave covers (h*64 q-rows) x (64 c-cols)
    const int h = w >> 2;
    const int c0 = (w & 3) * 64;
    f32x4 macc[4][4];
#pragma unroll
    for (int m = 0; m < 4; m++)
#pragma unroll
        for (int n = 0; n < 4; n++) macc[m][n] = (f32x4){0.f, 0.f, 0.f, 0.f};

    stage(s0, 0, 0);   // prologue: chunk 0 -> buf 0 (2 loads in flight)

    for (int st = 0; st < NTILES; ++st) {
        const int sbase = s0 + st * BS;
        f32x4 acc[2][4];
#pragma unroll
        for (int m = 0; m < 2; m++)
#pragma unroll
            for (int n = 0; n < 4; n++) acc[m][n] = (f32x4){0.f, 0.f, 0.f, 0.f};

        for (int kc = 0; kc < NKC; ++kc) {
            const int buf = kc & 1;
            int nkc = kc + 1, nsb = sbase;
            if (nkc == NKC) { nkc = 0; nsb = (st + 1 < NTILES) ? sbase + BS : sbase; }
            stage(nsb, nkc, buf ^ 1);                         // 4 outstanding
            asm volatile("s_waitcnt vmcnt(2)" ::: "memory");  // current chunk resident
            __builtin_amdgcn_s_barrier();                     // no drain
            __builtin_amdgcn_sched_barrier(0);

            const char* bq = (const char*)sQ[buf];
            const char* bs = (const char*)sS[buf];
            __builtin_amdgcn_s_setprio(1);
            {
                ll2 A0 = *(const ll2*)(bq + aoff[0]);
                ll2 A1 = *(const ll2*)(bq + aoff[1]);
                ll2 B0 = *(const ll2*)(bs + boff[0]);
                ll2 B1 = *(const ll2*)(bs + boff[1]);
                ll2 B2 = *(const ll2*)(bs + boff[2]);
                ll2 B3 = *(const ll2*)(bs + boff[3]);
#pragma unroll
                for (int k2 = 0; k2 < 2; k2++) {
                    acc[0][0] = __builtin_amdgcn_mfma_f32_16x16x32_fp8_fp8(A0[k2], B0[k2], acc[0][0], 0, 0, 0);
                    acc[0][1] = __builtin_amdgcn_mfma_f32_16x16x32_fp8_fp8(A0[k2], B1[k2], acc[0][1], 0, 0, 0);
                    acc[0][2] = __builtin_amdgcn_mfma_f32_16x16x32_fp8_fp8(A0[k2], B2[k2], acc[0][2], 0, 0, 0);
                    acc[0][3] = __builtin_amdgcn_mfma_f32_16x16x32_fp8_fp8(A0[k2], B3[k2], acc[0][3], 0, 0, 0);
                    acc[1][0] = __builtin_amdgcn_mfma_f32_16x16x32_fp8_fp8(A1[k2], B0[k2], acc[1][0], 0, 0, 0);
                    acc[1][1] = __builtin_amdgcn_mfma_f32_16x16x32_fp8_fp8(A1[k2], B1[k2], acc[1][1], 0, 0, 0);
                    acc[1][2] = __builtin_amdgcn_mfma_f32_16x16x32_fp8_fp8(A1[k2], B2[k2], acc[1][2], 0, 0, 0);
                    acc[1][3] = __builtin_amdgcn_mfma_f32_16x16x32_fp8_fp8(A1[k2], B3[k2], acc[1][3], 0, 0, 0);
                }
            }
            __builtin_amdgcn_s_setprio(0);
            __builtin_amdgcn_sched_barrier(0);
            __builtin_amdgcn_s_barrier();   // readers done; buf becomes prefetch target
        }

        // ---- exp2(P*scale*log2e/256) -> bf16 -> sP (swizzled [q][s]) ----
#pragma unroll
        for (int m = 0; m < 2; m++)
#pragma unroll
            for (int n = 0; n < 4; n++) {
                int q = wrow * 32 + m * 16 + l4 * 4;
                int s = wcol * 64 + n * 16 + l15;
#pragma unroll
                for (int r4 = 0; r4 < 4; r4++) {
                    u16 v = f2bf(exp2f(acc[m][n][r4] * sl2));
                    int qq = q + r4;
                    *(u16*)((char*)sP + (((qq * 256) + s * 2) ^ ((qq & 7) << 4))) = v;
                }
            }
        asm volatile("s_waitcnt lgkmcnt(0)" ::: "memory");
        __builtin_amdgcn_sched_barrier(0);
        __builtin_amdgcn_s_barrier();

        // ---- mass-GEMM: macc += expP @ onehot(labels), bf16 ----
#pragma unroll
        for (int kg = 0; kg < 4; ++kg) {
            int labk[8];
#pragma unroll
            for (int j = 0; j < 8; j++) labk[j] = slabAll[st * BS + kg * 32 + l4 * 8 + j];
            bf16x8 ap[4];
#pragma unroll
            for (int m = 0; m < 4; m++) {
                int r = h * 64 + m * 16 + l15;
                ap[m] = *(const bf16x8*)((const char*)sP +
                                         ((r * 256 + kg * 64 + l4 * 16) ^ ((r & 7) << 4)));
            }
#pragma unroll
            for (int n = 0; n < 4; n++) {
                int c = c0 + n * 16 + l15;
                bf16x8 bo;
#pragma unroll
                for (int j = 0; j < 8; j++) bo[j] = (labk[j] == c) ? (short)0x3F80 : (short)0;
                macc[0][n] = __builtin_amdgcn_mfma_f32_16x16x32_bf16(ap[0], bo, macc[0][n], 0, 0, 0);
                macc[1][n] = __builtin_amdgcn_mfma_f32_16x16x32_bf16(ap[1], bo, macc[1][n], 0, 0, 0);
                macc[2][n] = __builtin_amdgcn_mfma_f32_16x16x32_bf16(ap[2], bo, macc[2][n], 0, 0, 0);
                macc[3][n] = __builtin_amdgcn_mfma_f32_16x16x32_bf16(ap[3], bo, macc[3][n], 0, 0, 0);
            }
        }
        // sP rewritten only deep into next tile's kc loop -> safe
    }

    // ---- flush mass to global (NS adds per cell) ----
#pragma unroll
    for (int m = 0; m < 4; m++)
#pragma unroll
        for (int n = 0; n < 4; n++) {
            int c = c0 + n * 16 + l15;
#pragma unroll
            for (int r4 = 0; r4 < 4; r4++) {
                int q = qbase + h * 64 + m * 16 + l4 * 4 + r4;
                unsafeAtomicAdd(&massp[(size_t)q * C_N + c], macc[m][n][r4]);
            }
        }
}

// ---- finalize: normalize mass, log, prior, softmax ----
__global__ void k_final(const float* __restrict__ massp, const int* __restrict__ counts,
                        const float* __restrict__ cp_p, float* __restrict__ out) {
    __shared__ float sh[4];
    int q = blockIdx.x, c = threadIdx.x;
    float m = massp[(size_t)q * C_N + c];
    float denom = blkSum(m, sh);
    float cp = *cp_p;
    float logit = logf(fmaxf(m / denom, 1e-8f)) + cp * logf(fmaxf((float)counts[c], 1.f));
    float mx = blkMax(logit, sh);
    float e = __expf(logit - mx);
    float se = blkSum(e, sh);
    out[(size_t)q * C_N + c] = logit;
    out[(size_t)Q_N * C_N + C_N + (size_t)q * C_N + c] = e / se;
    if (q == 0) out[(size_t)Q_N * C_N + c] = (float)c;
}

extern "C" void kernel_launch(void* const* d_in, const int* in_sizes, int n_in,
                              void* d_out, int out_size, void* d_ws, size_t ws_size,
                              hipStream_t stream) {
    const float* sup = (const float*)d_in[0];
    const int* lab = (const int*)d_in[1];
    const float* qry = (const float*)d_in[2];
    const float* ls = (const float*)d_in[3];
    const float* cp = (const float*)d_in[4];
    float* out = (float*)d_out;
    char* ws = (char*)d_ws;

    float* massp = (float*)(ws + WS_MASSP);
    float* mu_raw = (float*)(ws + WS_MU);
    int* counts = (int*)(ws + WS_COUNTS);
    float* norms = (float*)(ws + WS_NORMS);
    u8* suppb = (u8*)(ws + WS_SUPPB);
    u8* qb = (u8*)(ws + WS_QB);

    hipMemsetAsync(massp, 0, Q_N * C_N * sizeof(float), stream);
    hipMemsetAsync(mu_raw, 0, 4096 + 1024, stream);   // mu_raw + counts (contiguous)
    k_prep<<<S_N / 16, 256, 0, stream>>>(sup, lab, mu_raw, norms, counts);
    k_trans<<<S_N + Q_N, 256, 0, stream>>>(sup, qry, norms, mu_raw, suppb, qb);
    k_mass<<<(Q_N / BQ) * NS, NTHR, 0, stream>>>(qb, suppb, lab, ls, massp);
    k_final<<<Q_N, 256, 0, stream>>>(massp, counts, cp, out);
}